// Round 7
// baseline (289.204 us; speedup 1.0000x reference)
//
#include <hip/hip_runtime.h>
#include <hip/hip_bf16.h>

// B=32, S=2048, H=512, fp32 in/out.
// scores = tanh(Y@W + b).w -> softmax(S) -> c_star = alpha@Y
// Root idea this round: make the GEMM's A-operand cheap. ysplit_k
// pre-converts Y (128MB fp32) -> Yh (64MB fp16, RNE) once; gemm then
// loads A as ONE 16B half8 per row (no cvt in K-loop, half the HBM-miss
// events), with a TWO-iteration A-prefetch (2x-unrolled body, static reg
// slots) so issue-to-use cover ~2 iters > HBM latency. B fp16 dbuf LDS
// via llds (verified chunk-XOR swizzle); steady-state wait vmcnt(6)
// retires only B(it) -- A waits are compiler-counted; nothing drains to 0.
// Tail: red_k (max + 1/sum), wsum1 reads Yh (64MB) with per-lane column
// ownership (no LDS transpose, no atomics), wsum2 sums 64 partials.
// ws_size guard: <72MB falls back to fp32-A templates (round-6 path).

#define Bsz 32
#define Ssz 2048
#define Hsz 512
#define Msz (Bsz * Ssz)   // 65536

using half8   = __attribute__((ext_vector_type(8))) _Float16;
using floatx4 = __attribute__((ext_vector_type(4))) float;

__device__ __forceinline__ void llds16(void* l, const void* g) {
  __builtin_amdgcn_global_load_lds((const __attribute__((address_space(1))) void*)g,
                                   (__attribute__((address_space(3))) void*)l, 16, 0, 0);
}

__device__ __forceinline__ float fast_tanh(float x) {
  const float e = __expf(2.f * x);
  return 1.f - 2.f / (e + 1.f);
}

// ---- Y fp32 -> fp16 (RNE), streaming ----
__global__ __launch_bounds__(256) void ysplit_k(const float* __restrict__ Y,
                                                _Float16* __restrict__ Yh) {
  const int t = blockIdx.x * 256 + threadIdx.x;   // 0..524287
  const float4* src = (const float4*)Y;
#pragma unroll
  for (int i = 0; i < 8; ++i) {
    const size_t gidx = (size_t)i * 524288 + t;   // 8-float groups, 4M total
    const float4 lo = src[gidx * 2];
    const float4 hi = src[gidx * 2 + 1];
    half8 h;
    h[0] = (_Float16)lo.x; h[1] = (_Float16)lo.y;
    h[2] = (_Float16)lo.z; h[3] = (_Float16)lo.w;
    h[4] = (_Float16)hi.x; h[5] = (_Float16)hi.y;
    h[6] = (_Float16)hi.z; h[7] = (_Float16)hi.w;
    *(half8*)&Yh[gidx * 8] = h;
  }
}

// ---- W[k][n] fp32 -> Wt[n][k] fp16 (transpose + RNE cast) ----
__global__ __launch_bounds__(256) void wsplit_k(const float* __restrict__ W,
                                                _Float16* __restrict__ Wt) {
  __shared__ float tile[32][33];
  const int bx = blockIdx.x & 15, by = blockIdx.x >> 4;
  const int tx = threadIdx.x & 31, ty = threadIdx.x >> 5;
#pragma unroll
  for (int i = 0; i < 4; ++i)
    tile[ty + 8 * i][tx] = W[(size_t)(by * 32 + ty + 8 * i) * Hsz + bx * 32 + tx];
  __syncthreads();
#pragma unroll
  for (int i = 0; i < 4; ++i) {
    const int n = bx * 32 + ty + 8 * i;
    const int k = by * 32 + tx;
    Wt[(size_t)n * Hsz + k] = (_Float16)tile[tx][ty + 8 * i];
  }
}

// ---- GEMM + tanh.w partial-score epilogue ----
// FP16A: A from Yh (1x16B/row, no cvt). !FP16A: A from Y fp32 (2x16B + cvt).
template <bool FP16A>
__global__ __launch_bounds__(256) void gemm_score_k(const void* __restrict__ Yv,
                                                    const _Float16* __restrict__ Wt,
                                                    const float* __restrict__ bvec,
                                                    const float* __restrict__ wvec,
                                                    float* __restrict__ scores4) {
  __shared__ __align__(16) _Float16 Bs[2][128 * 32];   // 2 x 8 KB fp16, chunk-swizzled
  const int tid = threadIdx.x;
  const int lane = tid & 63, wv = tid >> 6;
  const int lr = lane & 15, lq = lane >> 4;
  // XCD-aware decode: 4 nblk-siblings of one mblk share (g&7) -> same XCD L2.
  const int g = blockIdx.x;
  const int x = g & 7, q = g >> 3;
  const int nblk = q & 3;
  const int mblk = (q >> 2) * 8 + x;

  const _Float16* bW = Wt + (size_t)nblk * 128 * Hsz;

  // B staging: 512 chunks of 16B (row=chunk>>2), gptr permuted within the
  // row's 64B window (slot s holds global chunk s^((row>>1)&3)).
  int bL[2]; const _Float16* bG[2];
#pragma unroll
  for (int i = 0; i < 2; ++i) {
    const int cb = i * 256 + wv * 64;
    const int p = cb + lane;
    const int row = p >> 2;
    const int gc = (p & 3) ^ ((row >> 1) & 3);
    bL[i] = cb * 8;
    bG[i] = bW + (size_t)row * Hsz + gc * 8;
  }

  // A: wave-private rows mblk*128+wv*32+{0,16}+lr, k-slice [k0+lq*8,+8).
  const int arow = mblk * 128 + wv * 32 + lr;
  const _Float16* aH0 = (const _Float16*)Yv + (size_t)arow * Hsz + lq * 8;
  const _Float16* aH1 = aH0 + (size_t)16 * Hsz;
  const float*    aF0 = (const float*)Yv + (size_t)arow * Hsz + lq * 8;
  const float*    aF1 = aF0 + (size_t)16 * Hsz;

  floatx4 acc[2][8];
#pragma unroll
  for (int rf = 0; rf < 2; ++rf)
#pragma unroll
    for (int cf = 0; cf < 8; ++cf)
      acc[rf][cf] = (floatx4){0.f, 0.f, 0.f, 0.f};

  // Two static A-prefetch slots (avoid runtime-indexed arrays -> scratch).
  half8  hA0, hA1, hB0, hB1;           // FP16A slots
  float4 fA00, fA01, fA10, fA11;       // fp32 slot A
  float4 fB00, fB01, fB10, fB11;       // fp32 slot B

  // Prologue: B(0)->buf0 | A(0)->slotA | B(1)->buf1 | A(1)->slotB.
#pragma unroll
  for (int i = 0; i < 2; ++i) { llds16(&Bs[0][bL[i]], bG[i]); bG[i] += 32; }
  if constexpr (FP16A) {
    hA0 = *(const half8*)(aH0); hA1 = *(const half8*)(aH1);
  } else {
    fA00 = *(const float4*)(aF0);     fA01 = *(const float4*)(aF0 + 4);
    fA10 = *(const float4*)(aF1);     fA11 = *(const float4*)(aF1 + 4);
  }
#pragma unroll
  for (int i = 0; i < 2; ++i) { llds16(&Bs[1][bL[i]], bG[i]); bG[i] += 32; }
  if constexpr (FP16A) {
    hB0 = *(const half8*)(aH0 + 32); hB1 = *(const half8*)(aH1 + 32);
  } else {
    fB00 = *(const float4*)(aF0 + 32); fB01 = *(const float4*)(aF0 + 36);
    fB10 = *(const float4*)(aF1 + 32); fB11 = *(const float4*)(aF1 + 36);
  }

  // Body macro-free 2x unrolled loop; 8 double-iterations.
#pragma unroll 1
  for (int ii = 0; ii < 8; ++ii) {
    // ---------- even it = 2*ii, buffer 0, slot A ----------
    {
      const int it = 2 * ii;
      // Outstanding (FIFO): B(it)2, A(it)AL, B(it+1)2, A(it+1)AL.
      // Retire B(it) only; everything else stays in flight.
      if constexpr (FP16A) { asm volatile("s_waitcnt vmcnt(6)" ::: "memory"); }
      else                 { asm volatile("s_waitcnt vmcnt(10)" ::: "memory"); }
      __builtin_amdgcn_s_barrier();

      half8 a0, a1;
      if constexpr (FP16A) {
        a0 = hA0; a1 = hA1;   // compiler inserts counted vmcnt for slotA here
      } else {
        a0[0] = (_Float16)fA00.x; a0[1] = (_Float16)fA00.y;
        a0[2] = (_Float16)fA00.z; a0[3] = (_Float16)fA00.w;
        a0[4] = (_Float16)fA01.x; a0[5] = (_Float16)fA01.y;
        a0[6] = (_Float16)fA01.z; a0[7] = (_Float16)fA01.w;
        a1[0] = (_Float16)fA10.x; a1[1] = (_Float16)fA10.y;
        a1[2] = (_Float16)fA10.z; a1[3] = (_Float16)fA10.w;
        a1[4] = (_Float16)fA11.x; a1[5] = (_Float16)fA11.y;
        a1[6] = (_Float16)fA11.z; a1[7] = (_Float16)fA11.w;
      }
      // Prefetch A(it+2) into freed slot A (2-iteration cover).
      if (it < 14) {
        const int k2 = (it + 2) * 32;
        if constexpr (FP16A) {
          hA0 = *(const half8*)(aH0 + k2); hA1 = *(const half8*)(aH1 + k2);
        } else {
          fA00 = *(const float4*)(aF0 + k2);     fA01 = *(const float4*)(aF0 + k2 + 4);
          fA10 = *(const float4*)(aF1 + k2);     fA11 = *(const float4*)(aF1 + k2 + 4);
        }
      }
      const _Float16* Bsb = Bs[0];
#pragma unroll
      for (int cf = 0; cf < 8; ++cf) {
        const int nr = cf * 16 + lr;
        const half8 bf = *(const half8*)&Bsb[nr * 32 + (lq ^ ((nr >> 1) & 3)) * 8];
        acc[0][cf] = __builtin_amdgcn_mfma_f32_16x16x32_f16(a0, bf, acc[0][cf], 0, 0, 0);
        acc[1][cf] = __builtin_amdgcn_mfma_f32_16x16x32_f16(a1, bf, acc[1][cf], 0, 0, 0);
      }
      asm volatile("s_waitcnt lgkmcnt(0)" ::: "memory");
      __builtin_amdgcn_s_barrier();
      if (it < 14) {
#pragma unroll
        for (int i = 0; i < 2; ++i) { llds16(&Bs[0][bL[i]], bG[i]); bG[i] += 32; }
      }
    }
    // ---------- odd it = 2*ii+1, buffer 1, slot B ----------
    {
      const int it = 2 * ii + 1;
      if (it < 15) {
        if constexpr (FP16A) { asm volatile("s_waitcnt vmcnt(6)" ::: "memory"); }
        else                 { asm volatile("s_waitcnt vmcnt(10)" ::: "memory"); }
      } else {
        if constexpr (FP16A) { asm volatile("s_waitcnt vmcnt(2)" ::: "memory"); }
        else                 { asm volatile("s_waitcnt vmcnt(4)" ::: "memory"); }
      }
      __builtin_amdgcn_s_barrier();

      half8 a0, a1;
      if constexpr (FP16A) {
        a0 = hB0; a1 = hB1;
      } else {
        a0[0] = (_Float16)fB00.x; a0[1] = (_Float16)fB00.y;
        a0[2] = (_Float16)fB00.z; a0[3] = (_Float16)fB00.w;
        a0[4] = (_Float16)fB01.x; a0[5] = (_Float16)fB01.y;
        a0[6] = (_Float16)fB01.z; a0[7] = (_Float16)fB01.w;
        a1[0] = (_Float16)fB10.x; a1[1] = (_Float16)fB10.y;
        a1[2] = (_Float16)fB10.z; a1[3] = (_Float16)fB10.w;
        a1[4] = (_Float16)fB11.x; a1[5] = (_Float16)fB11.y;
        a1[6] = (_Float16)fB11.z; a1[7] = (_Float16)fB11.w;
      }
      if (it < 14) {
        const int k2 = (it + 2) * 32;
        if constexpr (FP16A) {
          hB0 = *(const half8*)(aH0 + k2); hB1 = *(const half8*)(aH1 + k2);
        } else {
          fB00 = *(const float4*)(aF0 + k2);     fB01 = *(const float4*)(aF0 + k2 + 4);
          fB10 = *(const float4*)(aF1 + k2);     fB11 = *(const float4*)(aF1 + k2 + 4);
        }
      }
      const _Float16* Bsb = Bs[1];
#pragma unroll
      for (int cf = 0; cf < 8; ++cf) {
        const int nr = cf * 16 + lr;
        const half8 bf = *(const half8*)&Bsb[nr * 32 + (lq ^ ((nr >> 1) & 3)) * 8];
        acc[0][cf] = __builtin_amdgcn_mfma_f32_16x16x32_f16(a0, bf, acc[0][cf], 0, 0, 0);
        acc[1][cf] = __builtin_amdgcn_mfma_f32_16x16x32_f16(a1, bf, acc[1][cf], 0, 0, 0);
      }
      asm volatile("s_waitcnt lgkmcnt(0)" ::: "memory");
      __builtin_amdgcn_s_barrier();
      if (it < 14) {
#pragma unroll
        for (int i = 0; i < 2; ++i) { llds16(&Bs[1][bL[i]], bG[i]); bG[i] += 32; }
      }
    }
  }

  // Epilogue: v = sum over all 128 cols of tanh(pre+b)*w; 16-lane shuffle
  // reduce; wave owns full rows -> direct per-lane store.
  float bb[8], ww[8];
#pragma unroll
  for (int cf = 0; cf < 8; ++cf) {
    const int col = nblk * 128 + cf * 16 + lr;
    bb[cf] = bvec[col];
    ww[cf] = wvec[col];
  }
#pragma unroll
  for (int rf = 0; rf < 2; ++rf) {
#pragma unroll
    for (int r = 0; r < 4; ++r) {
      float v = 0.f;
#pragma unroll
      for (int cf = 0; cf < 8; ++cf)
        v += fast_tanh(acc[rf][cf][r] + bb[cf]) * ww[cf];
      v += __shfl_xor(v, 1, 16);
      v += __shfl_xor(v, 2, 16);
      v += __shfl_xor(v, 4, 16);
      v += __shfl_xor(v, 8, 16);
      if (lr == 0)
        scores4[(size_t)nblk * Msz + mblk * 128 + wv * 32 + rf * 16 + lq * 4 + r] = v;
    }
  }
}

// ---- reduce: masked score-sum, per-b max and 1/sum(exp) ----
__global__ __launch_bounds__(1024) void red_k(const float* __restrict__ scores4,
                                              const float* __restrict__ mask,
                                              float* __restrict__ ssum,
                                              float* __restrict__ minv) {
  const int b = blockIdx.x, t = threadIdx.x;
  const int lane = t & 63, w = t >> 6;   // 16 waves
  __shared__ float rm[16], rs[16];
  float v[2];
  float mx = -3.4e38f;
#pragma unroll
  for (int i = 0; i < 2; ++i) {
    const int idx = b * Ssz + i * 1024 + t;
    float s = scores4[idx] + scores4[Msz + idx] + scores4[2 * Msz + idx] + scores4[3 * Msz + idx];
    s -= 1000.f * (1.f - mask[idx]);
    ssum[idx] = s;
    v[i] = s;
    mx = fmaxf(mx, s);
  }
  for (int off = 32; off > 0; off >>= 1) mx = fmaxf(mx, __shfl_xor(mx, off, 64));
  if (lane == 0) rm[w] = mx;
  __syncthreads();
  mx = rm[0];
#pragma unroll
  for (int i = 1; i < 16; ++i) mx = fmaxf(mx, rm[i]);
  float sum = __expf(v[0] - mx) + __expf(v[1] - mx);
  for (int off = 32; off > 0; off >>= 1) sum += __shfl_xor(sum, off, 64);
  if (lane == 0) rs[w] = sum;
  __syncthreads();
  if (t == 0) {
    float tot = rs[0];
#pragma unroll
    for (int i = 1; i < 16; ++i) tot += rs[i];
    minv[b * 2]     = mx;
    minv[b * 2 + 1] = 1.f / tot;
  }
}

// ---- wsum stage 1: alpha inline, per-lane column ownership, no atomics ----
// Grid Bsz*64; block (b,g) handles 32 rows; wave wv rows g*32+wv*8..+8;
// lane owns cols lane*8..+8 (one 16B load per row -> whole row = 1 wave-instr).
template <bool FP16Y>
__global__ __launch_bounds__(256) void wsum1_k(const float* __restrict__ ssum,
                                               const float* __restrict__ minv,
                                               const void* __restrict__ Yv,
                                               float* __restrict__ partial) {
  const int b = blockIdx.x >> 6, g = blockIdx.x & 63;
  const int t = threadIdx.x, lane = t & 63, wv = t >> 6;
  __shared__ float part[4][512];
  const int s0 = g * 32 + wv * 8;
  const float mx  = minv[b * 2];
  const float inv = minv[b * 2 + 1];
  const float* sl = ssum + b * Ssz + s0;

  float acc[8];
#pragma unroll
  for (int i = 0; i < 8; ++i) acc[i] = 0.f;

  if constexpr (FP16Y) {
    const _Float16* Yb = (const _Float16*)Yv + ((size_t)b * Ssz + s0) * Hsz + lane * 8;
#pragma unroll
    for (int j = 0; j < 8; ++j) {
      const float a = __expf(sl[j] - mx) * inv;
      const half8 y = *(const half8*)(Yb + (size_t)j * Hsz);
#pragma unroll
      for (int i = 0; i < 8; ++i) acc[i] = fmaf(a, (float)y[i], acc[i]);
    }
  } else {
    const float* Yb = (const float*)Yv + ((size_t)b * Ssz + s0) * Hsz + lane * 8;
#pragma unroll
    for (int j = 0; j < 8; ++j) {
      const float a = __expf(sl[j] - mx) * inv;
      const float4 y0 = *(const float4*)(Yb + (size_t)j * Hsz);
      const float4 y1 = *(const float4*)(Yb + (size_t)j * Hsz + 4);
      acc[0] = fmaf(a, y0.x, acc[0]); acc[1] = fmaf(a, y0.y, acc[1]);
      acc[2] = fmaf(a, y0.z, acc[2]); acc[3] = fmaf(a, y0.w, acc[3]);
      acc[4] = fmaf(a, y1.x, acc[4]); acc[5] = fmaf(a, y1.y, acc[5]);
      acc[6] = fmaf(a, y1.z, acc[6]); acc[7] = fmaf(a, y1.w, acc[7]);
    }
  }
  *(float4*)&part[wv][lane * 8]     = (float4){acc[0], acc[1], acc[2], acc[3]};
  *(float4*)&part[wv][lane * 8 + 4] = (float4){acc[4], acc[5], acc[6], acc[7]};
  __syncthreads();
#pragma unroll
  for (int i = 0; i < 2; ++i) {
    const int h = i * 256 + t;
    partial[((size_t)(b * 64 + g)) * Hsz + h] =
        part[0][h] + part[1][h] + part[2][h] + part[3][h];
  }
}

// ---- wsum stage 2: out[b][h] = sum over 64 partial slabs ----
__global__ __launch_bounds__(256) void wsum2_k(const float* __restrict__ partial,
                                               float* __restrict__ out) {
  const int b = blockIdx.x >> 1;
  const int h = (blockIdx.x & 1) * 256 + threadIdx.x;
  float s = 0.f;
#pragma unroll 8
  for (int g = 0; g < 64; ++g)
    s += partial[((size_t)(b * 64 + g)) * Hsz + h];
  out[b * Hsz + h] = s;
}

extern "C" void kernel_launch(void* const* d_in, const int* in_sizes, int n_in,
                              void* d_out, int out_size, void* d_ws, size_t ws_size,
                              hipStream_t stream) {
  (void)in_sizes; (void)n_in; (void)out_size;
  const float* Y    = (const float*)d_in[0];
  const float* mask = (const float*)d_in[1];
  const float* W    = (const float*)d_in[2];
  const float* bvec = (const float*)d_in[3];
  const float* wvec = (const float*)d_in[4];
  float* out = (float*)d_out;

  char* ws = (char*)d_ws;
  _Float16* Wt   = (_Float16*)ws;                            // 512 KB @ 0
  float* scores4 = (float*)(ws + ((size_t)1 << 20));         // 1 MB   @ 1M
  float* ssum    = (float*)(ws + ((size_t)2 << 20));         // 256 KB @ 2M
  float* minv    = (float*)(ws + ((size_t)2304 << 10));      // 256 B  @ 2.25M
  float* partial = (float*)(ws + ((size_t)3 << 20));         // 4 MB   @ 3M
  _Float16* Yh   = (_Float16*)(ws + ((size_t)8 << 20));      // 64 MB  @ 8M

  const bool useH = ws_size >= ((size_t)72 << 20);

  wsplit_k<<<256, 256, 0, stream>>>(W, Wt);
  if (useH) {
    ysplit_k<<<2048, 256, 0, stream>>>(Y, Yh);
    gemm_score_k<true><<<(Msz / 128) * 4, 256, 0, stream>>>(Yh, Wt, bvec, wvec, scores4);
  } else {
    gemm_score_k<false><<<(Msz / 128) * 4, 256, 0, stream>>>(Y, Wt, bvec, wvec, scores4);
  }
  red_k<<<Bsz, 1024, 0, stream>>>(scores4, mask, ssum, minv);
  if (useH) wsum1_k<true><<<Bsz * 64, 256, 0, stream>>>(ssum, minv, Yh, partial);
  else      wsum1_k<false><<<Bsz * 64, 256, 0, stream>>>(ssum, minv, Y, partial);
  wsum2_k<<<Bsz * 2, 256, 0, stream>>>(partial, out);
}

// Round 8
// 276.478 us; speedup vs baseline: 1.0460x; 1.0460x over previous
//
#include <hip/hip_runtime.h>
#include <hip/hip_bf16.h>

// B=32, S=2048, H=512, fp32 in/out.
// scores = tanh(Y@W + b).w -> softmax(S) -> c_star = alpha@Y
// FULLY FUSED flash-style: 512 blocks, one per 128-row slab of (b,s).
// Phase 1: score GEMM, 8 n-tiles of 64 cols; Wt tile (64x512 fp16, 64KB)
//   staged in LDS per tile (llds + chunk-XOR swizzle); A loaded from Y
//   ONCE during nt=0 (global->reg->fp16) and kept in 128 VGPRs; nt 1..7
//   run from registers. K complete per n-tile -> tanh(pre+b)*w reduced
//   to per-row score partials, accumulated across tiles.
// Phase 2: block-local softmax partial (m_blk, sum_blk, p=exp(s-m_blk)).
// Phase 3: U[512] = sum_rows p*Y from the SAME A registers (no Y re-read).
// combine_k: exact flash merge of 16 slab-partials per batch -> out.
// Y is read from HBM exactly once for the entire problem.

#define Bsz 32
#define Ssz 2048
#define Hsz 512
#define Msz (Bsz * Ssz)   // 65536

using half8   = __attribute__((ext_vector_type(8))) _Float16;
using floatx4 = __attribute__((ext_vector_type(4))) float;

__device__ __forceinline__ void llds16(void* l, const void* g) {
  __builtin_amdgcn_global_load_lds((const __attribute__((address_space(1))) void*)g,
                                   (__attribute__((address_space(3))) void*)l, 16, 0, 0);
}

__device__ __forceinline__ float fast_tanh(float x) {
  const float e = __expf(2.f * x);
  return 1.f - 2.f / (e + 1.f);
}

// ---- W[k][n] fp32 -> Wt[n][k] fp16 (transpose + RNE cast) ----
__global__ __launch_bounds__(256) void wsplit_k(const float* __restrict__ W,
                                                _Float16* __restrict__ Wt) {
  __shared__ float tile[32][33];
  const int bx = blockIdx.x & 15, by = blockIdx.x >> 4;
  const int tx = threadIdx.x & 31, ty = threadIdx.x >> 5;
#pragma unroll
  for (int i = 0; i < 4; ++i)
    tile[ty + 8 * i][tx] = W[(size_t)(by * 32 + ty + 8 * i) * Hsz + bx * 32 + tx];
  __syncthreads();
#pragma unroll
  for (int i = 0; i < 4; ++i) {
    const int n = bx * 32 + ty + 8 * i;
    const int k = by * 32 + tx;
    Wt[(size_t)n * Hsz + k] = (_Float16)tile[tx][ty + 8 * i];
  }
}

// ---- fused: scores + block softmax partial + weighted sum partial ----
__global__ __launch_bounds__(256, 2) void fused_k(const float* __restrict__ Y,
                                                  const _Float16* __restrict__ Wt,
                                                  const float* __restrict__ bvec,
                                                  const float* __restrict__ wvec,
                                                  const float* __restrict__ mask,
                                                  float* __restrict__ pU,
                                                  float* __restrict__ pM,
                                                  float* __restrict__ pS) {
  __shared__ __align__(16) _Float16 Bs[64 * 512];   // 64 KB Wt tile, chunk-swizzled
  __shared__ float U_lds[4][512];                   // 8 KB per-wave U partials
  __shared__ float s_lds[128], p_lds[128];
  __shared__ float rm[4], rs[4];

  const int tid = threadIdx.x;
  const int lane = tid & 63, wv = tid >> 6;
  const int lr = lane & 15, lq = lane >> 4;
  const int blk = blockIdx.x;          // 0..511
  const int row0 = blk * 128;          // global (b,s) row base

  // A rows for this lane: local rows wv*32+lr and wv*32+16+lr; k-slice lq*8..+8
  // per k-step (verified A-frag lane mapping: row=..+lr, k=k0+lq*8).
  const float* aR0 = Y + (size_t)(row0 + wv * 32 + lr) * Hsz + lq * 8;
  const float* aR1 = aR0 + (size_t)16 * Hsz;

  half8 a0[16], a1[16];   // A held fp16 for all 16 k-steps (128 VGPR)
  float sc[2][4];         // per-row score partials [rf][r]
#pragma unroll
  for (int rf = 0; rf < 2; ++rf)
#pragma unroll
    for (int r = 0; r < 4; ++r) sc[rf][r] = 0.f;

#pragma unroll 1
  for (int nt = 0; nt < 8; ++nt) {
    // Stage Wt tile nt: 4096 chunks of 16B; row=chunk>>6, slot=chunk&63;
    // slot s holds global chunk s^(row&7) (involution; read applies same XOR).
#pragma unroll
    for (int i = 0; i < 16; ++i) {
      const int p = i * 256 + tid;
      const int row = p >> 6, slot = p & 63;
      const int gc = slot ^ (row & 7);
      llds16(&Bs[p * 8], Wt + (size_t)(nt * 64 + row) * Hsz + gc * 8);
    }
    __syncthreads();

    floatx4 acc[2][4];
#pragma unroll
    for (int rf = 0; rf < 2; ++rf)
#pragma unroll
      for (int cf = 0; cf < 4; ++cf)
        acc[rf][cf] = (floatx4){0.f, 0.f, 0.f, 0.f};

    if (nt == 0) {
      // A streams from HBM here (once), cvt fp16, cached in regs.
#pragma unroll
      for (int kk = 0; kk < 16; ++kk) {
        const float4 f00 = *(const float4*)(aR0 + kk * 32);
        const float4 f01 = *(const float4*)(aR0 + kk * 32 + 4);
        const float4 f10 = *(const float4*)(aR1 + kk * 32);
        const float4 f11 = *(const float4*)(aR1 + kk * 32 + 4);
        half8 h0, h1;
        h0[0] = (_Float16)f00.x; h0[1] = (_Float16)f00.y;
        h0[2] = (_Float16)f00.z; h0[3] = (_Float16)f00.w;
        h0[4] = (_Float16)f01.x; h0[5] = (_Float16)f01.y;
        h0[6] = (_Float16)f01.z; h0[7] = (_Float16)f01.w;
        h1[0] = (_Float16)f10.x; h1[1] = (_Float16)f10.y;
        h1[2] = (_Float16)f10.z; h1[3] = (_Float16)f10.w;
        h1[4] = (_Float16)f11.x; h1[5] = (_Float16)f11.y;
        h1[6] = (_Float16)f11.z; h1[7] = (_Float16)f11.w;
        a0[kk] = h0; a1[kk] = h1;
#pragma unroll
        for (int cf = 0; cf < 4; ++cf) {
          const int nr = cf * 16 + lr;
          const int slot = (kk * 4 + lq) ^ (nr & 7);
          const half8 bf = *(const half8*)&Bs[(nr * 64 + slot) * 8];
          acc[0][cf] = __builtin_amdgcn_mfma_f32_16x16x32_f16(h0, bf, acc[0][cf], 0, 0, 0);
          acc[1][cf] = __builtin_amdgcn_mfma_f32_16x16x32_f16(h1, bf, acc[1][cf], 0, 0, 0);
        }
      }
    } else {
      // Pure reg + LDS: compiler free to interleave ds_read/MFMA.
#pragma unroll
      for (int kk = 0; kk < 16; ++kk) {
#pragma unroll
        for (int cf = 0; cf < 4; ++cf) {
          const int nr = cf * 16 + lr;
          const int slot = (kk * 4 + lq) ^ (nr & 7);
          const half8 bf = *(const half8*)&Bs[(nr * 64 + slot) * 8];
          acc[0][cf] = __builtin_amdgcn_mfma_f32_16x16x32_f16(a0[kk], bf, acc[0][cf], 0, 0, 0);
          acc[1][cf] = __builtin_amdgcn_mfma_f32_16x16x32_f16(a1[kk], bf, acc[1][cf], 0, 0, 0);
        }
      }
    }

    // Score partial for this 64-col slice: v = sum_cf tanh(pre+b)*w,
    // shuffle-reduced over the 16 col-lanes (verified epilogue pattern).
    float bb[4], ww[4];
#pragma unroll
    for (int cf = 0; cf < 4; ++cf) {
      const int col = nt * 64 + cf * 16 + lr;
      bb[cf] = bvec[col];
      ww[cf] = wvec[col];
    }
#pragma unroll
    for (int rf = 0; rf < 2; ++rf) {
#pragma unroll
      for (int r = 0; r < 4; ++r) {
        float v = 0.f;
#pragma unroll
        for (int cf = 0; cf < 4; ++cf)
          v += fast_tanh(acc[rf][cf][r] + bb[cf]) * ww[cf];
        v += __shfl_xor(v, 1, 16);
        v += __shfl_xor(v, 2, 16);
        v += __shfl_xor(v, 4, 16);
        v += __shfl_xor(v, 8, 16);
        sc[rf][r] += v;
      }
    }
    __syncthreads();   // all Bs reads done before next tile's staging
  }

  // ---- Phase 2: block-local softmax partial over the 128 rows ----
  if (lr == 0) {
#pragma unroll
    for (int rf = 0; rf < 2; ++rf)
#pragma unroll
      for (int r = 0; r < 4; ++r)
        s_lds[wv * 32 + rf * 16 + lq * 4 + r] = sc[rf][r];
  }
  __syncthreads();
  float v = -3.4e38f;
  if (tid < 128) v = s_lds[tid] - 1000.f * (1.f - mask[row0 + tid]);
  float m = v;
  for (int off = 32; off > 0; off >>= 1) m = fmaxf(m, __shfl_xor(m, off, 64));
  if (lane == 0) rm[wv] = m;
  __syncthreads();
  m = fmaxf(fmaxf(rm[0], rm[1]), fmaxf(rm[2], rm[3]));
  float p = (tid < 128) ? __expf(v - m) : 0.f;
  if (tid < 128) p_lds[tid] = p;
  float sum = p;
  for (int off = 32; off > 0; off >>= 1) sum += __shfl_xor(sum, off, 64);
  if (lane == 0) rs[wv] = sum;
  __syncthreads();
  sum = rs[0] + rs[1] + rs[2] + rs[3];

  // ---- Phase 3: U = sum_rows p*Y from the A registers (no Y re-read) ----
  const float p0 = p_lds[wv * 32 + lr];
  const float p1 = p_lds[wv * 32 + 16 + lr];
#pragma unroll
  for (int kk = 0; kk < 16; ++kk) {
    float u[8];
#pragma unroll
    for (int j = 0; j < 8; ++j)
      u[j] = p0 * (float)a0[kk][j] + p1 * (float)a1[kk][j];
#pragma unroll
    for (int off = 1; off < 16; off <<= 1)
#pragma unroll
      for (int j = 0; j < 8; ++j) u[j] += __shfl_xor(u[j], off, 16);
    if (lr == 0) {
      *(float4*)&U_lds[wv][kk * 32 + lq * 8]     = (float4){u[0], u[1], u[2], u[3]};
      *(float4*)&U_lds[wv][kk * 32 + lq * 8 + 4] = (float4){u[4], u[5], u[6], u[7]};
    }
  }
  __syncthreads();
#pragma unroll
  for (int i = 0; i < 2; ++i) {
    const int h = i * 256 + tid;
    pU[(size_t)blk * Hsz + h] =
        U_lds[0][h] + U_lds[1][h] + U_lds[2][h] + U_lds[3][h];
  }
  if (tid == 0) { pM[blk] = m; pS[blk] = sum; }
}

// ---- combine: exact flash merge of 16 slab-partials per batch ----
__global__ __launch_bounds__(256) void combine_k(const float* __restrict__ pU,
                                                 const float* __restrict__ pM,
                                                 const float* __restrict__ pS,
                                                 float* __restrict__ out) {
  const int b = blockIdx.x, t = threadIdx.x;
  float m = -3.4e38f;
#pragma unroll
  for (int j = 0; j < 16; ++j) m = fmaxf(m, pM[b * 16 + j]);
  float D = 0.f, u0 = 0.f, u1 = 0.f;
#pragma unroll
  for (int j = 0; j < 16; ++j) {
    const float e = __expf(pM[b * 16 + j] - m);
    D  += e * pS[b * 16 + j];
    u0 += e * pU[(size_t)(b * 16 + j) * Hsz + t];
    u1 += e * pU[(size_t)(b * 16 + j) * Hsz + 256 + t];
  }
  const float inv = 1.f / D;
  out[b * Hsz + t]       = u0 * inv;
  out[b * Hsz + 256 + t] = u1 * inv;
}

extern "C" void kernel_launch(void* const* d_in, const int* in_sizes, int n_in,
                              void* d_out, int out_size, void* d_ws, size_t ws_size,
                              hipStream_t stream) {
  (void)in_sizes; (void)n_in; (void)out_size; (void)ws_size;
  const float* Y    = (const float*)d_in[0];
  const float* mask = (const float*)d_in[1];
  const float* W    = (const float*)d_in[2];
  const float* bvec = (const float*)d_in[3];
  const float* wvec = (const float*)d_in[4];
  float* out = (float*)d_out;

  char* ws = (char*)d_ws;
  _Float16* Wt = (_Float16*)ws;                        // 512 KB @ 0
  float* pU    = (float*)(ws + ((size_t)1 << 20));     // 1 MB   @ 1M (512 x 512)
  float* pM    = (float*)(ws + ((size_t)2 << 20));     // 2 KB   @ 2M
  float* pS    = (float*)(ws + ((size_t)2 << 20) + 4096);

  wsplit_k<<<256, 256, 0, stream>>>(W, Wt);
  fused_k<<<512, 256, 0, stream>>>(Y, Wt, bvec, wvec, mask, pU, pM, pS);
  combine_k<<<Bsz, 256, 0, stream>>>(pU, pM, pS, out);
}